// Round 10
// baseline (1850.724 us; speedup 1.0000x reference)
//
#include <hip/hip_runtime.h>

#define T_STEPS 2048
#define BATCH   128
#define HID     100     // LSTM hidden size
#define HP      112     // padded hidden length (multiple of 16)
#define NTH     896     // 14 waves of 64; 8 lanes per (padded) hidden unit

// DPP quad_perm broadcast (VALU pipe, immediate ctrl)
template <int CTRL>
__device__ __forceinline__ float dpp_mov(float v) {
    int y = __builtin_amdgcn_update_dpp(0, __float_as_int(v), CTRL, 0xF, 0xF, true);
    return __int_as_float(y);
}

__global__ __launch_bounds__(NTH)
void lstm_caviar_kernel(
    const float* __restrict__ x,      // [T, B, 1]
    const float* __restrict__ W_ih,   // [400, 1]
    const float* __restrict__ W_hh,   // [400, 100]
    const float* __restrict__ b_ih,   // [400]
    const float* __restrict__ b_hh,   // [400]
    const float* __restrict__ W1,     // [64, 100]
    const float* __restrict__ b1,     // [64]
    const float* __restrict__ W2,     // [1, 64]
    const float* __restrict__ b2,     // [1]
    float* __restrict__ out)          // [1]
{
    __shared__ __align__(16) float h_buf[2][HP];
    __shared__ float x_lds[T_STEPS];
    __shared__ float red_lds[64];

    const int tid  = threadIdx.x;
    const int g    = tid & 3;          // gate owned by this lane (i,f,g,o)
    const int ksub = (tid >> 2) & 1;   // k-half within the gate (2 lanes/gate)
    const int j    = tid >> 3;         // (padded) hidden unit, 0..111
    const bool jact = (j < HID);

    // stage batch-0 inputs (x[t,0,0] = flat[t*BATCH]) into LDS once
    for (int t = tid; t < T_STEPS; t += NTH)
        x_lds[t] = x[t * BATCH];
    if (tid < HP) { h_buf[0][tid] = 0.0f; h_buf[1][tid] = 0.0f; }

    // Preload this lane's 56 weights: k = 8*q + 4*ksub + d, q=0..13, d=0..3.
    // Units j>=100 get zero weights/bias -> their h stays exactly 0 forever,
    // so the loop needs no activity guards. wi/bias pre-scaled by 0.5 so the
    // 2-lane xor4 reduction sums them to exactly 1x.
    const int row = g * HID + (jact ? j : 0);
    const float* wr = W_hh + row * HID;
    float w[56];
    #pragma unroll
    for (int q = 0; q < 14; ++q) {
        #pragma unroll
        for (int d = 0; d < 4; ++d) {
            const int k = 8 * q + 4 * ksub + d;
            w[q * 4 + d] = (jact && k < HID) ? wr[k] : 0.0f;
        }
    }
    float wi = jact ? 0.5f * W_ih[row] : 0.0f;
    float bs = jact ? 0.5f * (b_ih[row] + b_hh[row]) : 0.0f;

    const bool is_g = (g == 2);
    float c = 0.0f;
    __syncthreads();

    for (int t = 0; t < T_STEPS; ++t) {
        // light in-loop pin: keeps the 56 weights from being rematerialized
        #pragma unroll
        for (int k = 0; k < 56; ++k)
            asm volatile("" : "+v"(w[k]));
        asm volatile("" : "+v"(wi), "+v"(bs));

        const float* hb = h_buf[t & 1];
        const float xt = x_lds[t];

        float acc = fmaf(wi, xt, bs);
        #pragma unroll
        for (int q = 0; q < 14; ++q) {
            const float4 hv = *(const float4*)(hb + 8 * q + 4 * ksub); // 16B aligned
            acc = fmaf(w[q*4+0], hv.x, acc);
            acc = fmaf(w[q*4+1], hv.y, acc);
            acc = fmaf(w[q*4+2], hv.z, acc);
            acc = fmaf(w[q*4+3], hv.w, acc);
        }

        // reduce across the 2 k-half lanes (xor lane^4): both get the full sum
        acc += __int_as_float(__builtin_amdgcn_ds_swizzle(__float_as_int(acc), 0x101F));

        // this lane activates its own gate (i,f,o: sigmoid; g: tanh = 2*sig(2x)-1)
        const float pre = is_g ? (acc + acc) : acc;
        const float e   = __expf(-pre);
        const float v   = 1.0f / (1.0f + e);
        const float act = is_g ? (v + v - 1.0f) : v;

        // quad broadcast: lanes (g=0..3) of this (j,ksub) group share all 4 gates
        const float ig = dpp_mov<0x00>(act);
        const float fg = dpp_mov<0x55>(act);
        const float gg = dpp_mov<0xAA>(act);
        const float og = dpp_mov<0xFF>(act);

        c = fmaf(fg, c, ig * gg);
        const float e2 = __expf(-2.0f * c);
        const float th = 2.0f / (1.0f + e2) - 1.0f;
        const float h  = og * th;

        if ((tid & 7) == 0)
            h_buf[(t + 1) & 1][j] = h;   // j in [0,112); j>=100 writes exact 0
        __syncthreads();
    }

    // head: lin = W1 @ h + b1 (64), out = W2 @ lin + b2 (scalar)
    if (tid < 64) {
        const float* r = W1 + tid * HID;
        const float* hf = h_buf[0];   // T even -> final h in buf 0
        float a = 0.0f;
        for (int k = 0; k < HID; ++k)
            a = fmaf(r[k], hf[k], a);
        red_lds[tid] = a + b1[tid];
    }
    __syncthreads();
    if (tid == 0) {
        float a = b2[0];
        for (int k = 0; k < 64; ++k)
            a = fmaf(W2[k], red_lds[k], a);
        out[0] = a;
    }
}

extern "C" void kernel_launch(void* const* d_in, const int* in_sizes, int n_in,
                              void* d_out, int out_size, void* d_ws, size_t ws_size,
                              hipStream_t stream) {
    lstm_caviar_kernel<<<1, NTH, 0, stream>>>(
        (const float*)d_in[0],  // input_seq
        (const float*)d_in[1],  // W_ih
        (const float*)d_in[2],  // W_hh
        (const float*)d_in[3],  // b_ih
        (const float*)d_in[4],  // b_hh
        (const float*)d_in[5],  // W1
        (const float*)d_in[6],  // b1
        (const float*)d_in[7],  // W2
        (const float*)d_in[8],  // b2
        (float*)d_out);
}

// Round 12
// 1605.076 us; speedup vs baseline: 1.1530x; 1.1530x over previous
//
#include <hip/hip_runtime.h>

#define T_STEPS 2048
#define BATCH   128
#define HID     100     // LSTM hidden size
#define KP      112     // padded k-extent of the matvec (multiple of 16)
#define JP      128     // padded hidden units = NTH/8
#define NTH     1024    // 16 waves of 64 -> exactly 4 waves per SIMD

// DPP quad_perm broadcast (VALU pipe, immediate ctrl)
template <int CTRL>
__device__ __forceinline__ float dpp_mov(float v) {
    int y = __builtin_amdgcn_update_dpp(0, __float_as_int(v), CTRL, 0xF, 0xF, true);
    return __int_as_float(y);
}

__global__ __launch_bounds__(NTH)
__attribute__((amdgpu_waves_per_eu(4, 4)))   // exactly 4 waves/EU -> 128-VGPR budget
void lstm_caviar_kernel(
    const float* __restrict__ x,      // [T, B, 1]
    const float* __restrict__ W_ih,   // [400, 1]
    const float* __restrict__ W_hh,   // [400, 100]
    const float* __restrict__ b_ih,   // [400]
    const float* __restrict__ b_hh,   // [400]
    const float* __restrict__ W1,     // [64, 100]
    const float* __restrict__ b1,     // [64]
    const float* __restrict__ W2,     // [1, 64]
    const float* __restrict__ b2,     // [1]
    float* __restrict__ out)          // [1]
{
    __shared__ __align__(16) float h_buf[2][KP];
    __shared__ float x_lds[T_STEPS];
    __shared__ float red_lds[64];

    const int tid  = threadIdx.x;
    const int g    = tid & 3;          // gate owned by this lane (i,f,g,o)
    const int ksub = (tid >> 2) & 1;   // k-half within the gate (2 lanes/gate)
    const int j    = tid >> 3;         // (padded) hidden unit, 0..127
    const bool jact = (j < HID);

    // stage batch-0 inputs (x[t,0,0] = flat[t*BATCH]) into LDS once
    for (int t = tid; t < T_STEPS; t += NTH)
        x_lds[t] = x[t * BATCH];
    if (tid < KP) { h_buf[0][tid] = 0.0f; h_buf[1][tid] = 0.0f; }

    // Preload this lane's 56 weights: k = 8*q + 4*ksub + d, q=0..13, d=0..3.
    // Units j>=100 get zero weights/bias -> their h stays exactly 0 forever,
    // so the loop needs no activity guards. wi/bias pre-scaled by 0.5 so the
    // 2-lane xor4 reduction sums them to exactly 1x.
    const int row = g * HID + (jact ? j : 0);
    const float* wr = W_hh + row * HID;
    float w[56];
    #pragma unroll
    for (int q = 0; q < 14; ++q) {
        #pragma unroll
        for (int d = 0; d < 4; ++d) {
            const int k = 8 * q + 4 * ksub + d;
            w[q * 4 + d] = (jact && k < HID) ? wr[k] : 0.0f;
        }
    }
    float wi = jact ? 0.5f * W_ih[row] : 0.0f;
    float bs = jact ? 0.5f * (b_ih[row] + b_hh[row]) : 0.0f;

    const bool is_g = (g == 2);
    float c = 0.0f;
    __syncthreads();

    for (int t = 0; t < T_STEPS; ++t) {
        // light in-loop pin: zero instructions when already VGPR-resident,
        // but blocks rematerialization/spill of the weight pool
        #pragma unroll
        for (int k = 0; k < 56; ++k)
            asm volatile("" : "+v"(w[k]));
        asm volatile("" : "+v"(wi), "+v"(bs));

        const float* hb = h_buf[t & 1];
        const float xt = x_lds[t];

        float acc = fmaf(wi, xt, bs);
        #pragma unroll
        for (int q = 0; q < 14; ++q) {
            const float4 hv = *(const float4*)(hb + 8 * q + 4 * ksub); // 16B aligned
            acc = fmaf(w[q*4+0], hv.x, acc);
            acc = fmaf(w[q*4+1], hv.y, acc);
            acc = fmaf(w[q*4+2], hv.z, acc);
            acc = fmaf(w[q*4+3], hv.w, acc);
        }

        // reduce across the 2 k-half lanes (xor lane^4): both get the full sum
        acc += __int_as_float(__builtin_amdgcn_ds_swizzle(__float_as_int(acc), 0x101F));

        // this lane activates its own gate (i,f,o: sigmoid; g: tanh = 2*sig(2x)-1)
        const float pre = is_g ? (acc + acc) : acc;
        const float e   = __expf(-pre);
        const float v   = 1.0f / (1.0f + e);
        const float act = is_g ? (v + v - 1.0f) : v;

        // quad broadcast: lanes (g=0..3) of this (j,ksub) group share all 4 gates
        const float ig = dpp_mov<0x00>(act);
        const float fg = dpp_mov<0x55>(act);
        const float gg = dpp_mov<0xAA>(act);
        const float og = dpp_mov<0xFF>(act);

        c = fmaf(fg, c, ig * gg);
        const float e2 = __expf(-2.0f * c);
        const float th = 2.0f / (1.0f + e2) - 1.0f;
        const float h  = og * th;

        if ((tid & 7) == 0 && j < KP)
            h_buf[(t + 1) & 1][j] = h;   // j in [0,112); j>=100 writes exact 0
        __syncthreads();
    }

    // head: lin = W1 @ h + b1 (64), out = W2 @ lin + b2 (scalar)
    if (tid < 64) {
        const float* r = W1 + tid * HID;
        const float* hf = h_buf[0];   // T even -> final h in buf 0
        float a = 0.0f;
        for (int k = 0; k < HID; ++k)
            a = fmaf(r[k], hf[k], a);
        red_lds[tid] = a + b1[tid];
    }
    __syncthreads();
    if (tid == 0) {
        float a = b2[0];
        for (int k = 0; k < 64; ++k)
            a = fmaf(W2[k], red_lds[k], a);
        out[0] = a;
    }
}

extern "C" void kernel_launch(void* const* d_in, const int* in_sizes, int n_in,
                              void* d_out, int out_size, void* d_ws, size_t ws_size,
                              hipStream_t stream) {
    lstm_caviar_kernel<<<1, NTH, 0, stream>>>(
        (const float*)d_in[0],  // input_seq
        (const float*)d_in[1],  // W_ih
        (const float*)d_in[2],  // W_hh
        (const float*)d_in[3],  // b_ih
        (const float*)d_in[4],  // b_hh
        (const float*)d_in[5],  // W1
        (const float*)d_in[6],  // b1
        (const float*)d_in[7],  // W2
        (const float*)d_in[8],  // b2
        (float*)d_out);
}

// Round 13
// 1192.058 us; speedup vs baseline: 1.5525x; 1.3465x over previous
//
#include <hip/hip_runtime.h>

#define T_STEPS 2048
#define BATCH   128
#define HID     100     // LSTM hidden size
#define KP      112     // padded hidden length (multiple of 16)
#define NTH     448     // 7 waves of 64

typedef _Float16 h2v __attribute__((ext_vector_type(2)));

// DPP quad_perm helpers (VALU pipe, immediate ctrl)
template <int CTRL>
__device__ __forceinline__ float dpp_mov(float v) {
    int y = __builtin_amdgcn_update_dpp(0, __float_as_int(v), CTRL, 0xF, 0xF, true);
    return __int_as_float(y);
}
template <int CTRL>
__device__ __forceinline__ float dpp_add(float v) {
    return v + dpp_mov<CTRL>(v);
}

__global__ __launch_bounds__(NTH)
__attribute__((amdgpu_waves_per_eu(2, 2)))
void lstm_caviar_kernel(
    const float* __restrict__ x,      // [T, B, 1]
    const float* __restrict__ W_ih,   // [400, 1]
    const float* __restrict__ W_hh,   // [400, 100]
    const float* __restrict__ b_ih,   // [400]
    const float* __restrict__ b_hh,   // [400]
    const float* __restrict__ W1,     // [64, 100]
    const float* __restrict__ b1,     // [64]
    const float* __restrict__ W2,     // [1, 64]
    const float* __restrict__ b2,     // [1]
    float* __restrict__ out)          // [1]
{
    __shared__ __align__(16) _Float16 h_buf[2][KP];   // 224 B rows, 16B-aligned
    __shared__ float x_lds[T_STEPS];
    __shared__ float red_lds[64];

    const int tid = threadIdx.x;
    const int j   = tid >> 2;     // hidden unit owned by this quad
    const int s   = tid & 3;      // k-split / gate-specialization lane
    const bool active = (j < HID);

    // stage batch-0 inputs (x[t,0,0] = flat[t*BATCH]) into LDS once
    for (int t = tid; t < T_STEPS; t += NTH)
        x_lds[t] = x[t * BATCH];
    if (tid < KP) { h_buf[0][tid] = (_Float16)0.0f; h_buf[1][tid] = (_Float16)0.0f; }

    // Preload W_hh as f16 pairs: lane covers k = 16*m + 4*s + {0,1},{2,3};
    // 56 packed regs hold 112 weights. wi/bias pre-scaled by 0.25 so the
    // 4-lane butterfly sums them to exactly 1x.
    h2v w2[4][14];
    float wi4[4], bs4[4];
    #pragma unroll
    for (int g = 0; g < 4; ++g) {
        const int gate = g * HID + (active ? j : 0);
        const float* row = W_hh + gate * HID;
        #pragma unroll
        for (int m = 0; m < 7; ++m) {
            #pragma unroll
            for (int p = 0; p < 2; ++p) {
                const int k0 = 16 * m + 4 * s + 2 * p;
                h2v v;
                v.x = (_Float16)((active && k0 + 0 < HID) ? row[k0 + 0] : 0.0f);
                v.y = (_Float16)((active && k0 + 1 < HID) ? row[k0 + 1] : 0.0f);
                w2[g][m * 2 + p] = v;
            }
        }
        wi4[g] = active ? 0.25f * W_ih[gate] : 0.0f;
        bs4[g] = active ? 0.25f * (b_ih[gate] + b_hh[gate]) : 0.0f;
    }

    const bool is_g = (s == 2);
    float c = 0.0f;
    __syncthreads();

    for (int t = 0; t < T_STEPS; ++t) {
        // light pin: discourage remat/spill of the 56-reg packed pool
        #pragma unroll
        for (int g = 0; g < 4; ++g) {
            #pragma unroll
            for (int k = 0; k < 14; ++k)
                asm volatile("" : "+v"(w2[g][k]));
            asm volatile("" : "+v"(wi4[g]), "+v"(bs4[g]));
        }

        const _Float16* hb = h_buf[t & 1];
        const float xt = x_lds[t];

        float acc0 = fmaf(wi4[0], xt, bs4[0]);
        float acc1 = fmaf(wi4[1], xt, bs4[1]);
        float acc2 = fmaf(wi4[2], xt, bs4[2]);
        float acc3 = fmaf(wi4[3], xt, bs4[3]);

        #pragma unroll
        for (int m = 0; m < 7; ++m) {
            // 8B aligned: byte offset 32*m + 8*s
            const h2v* hp = (const h2v*)(hb + 16 * m + 4 * s);
            const h2v hlo = hp[0];
            const h2v hhi = hp[1];
            acc0 = __builtin_amdgcn_fdot2(w2[0][m*2+0], hlo, acc0, false);
            acc0 = __builtin_amdgcn_fdot2(w2[0][m*2+1], hhi, acc0, false);
            acc1 = __builtin_amdgcn_fdot2(w2[1][m*2+0], hlo, acc1, false);
            acc1 = __builtin_amdgcn_fdot2(w2[1][m*2+1], hhi, acc1, false);
            acc2 = __builtin_amdgcn_fdot2(w2[2][m*2+0], hlo, acc2, false);
            acc2 = __builtin_amdgcn_fdot2(w2[2][m*2+1], hhi, acc2, false);
            acc3 = __builtin_amdgcn_fdot2(w2[3][m*2+0], hlo, acc3, false);
            acc3 = __builtin_amdgcn_fdot2(w2[3][m*2+1], hhi, acc3, false);
        }

        // quad butterfly (VALU/DPP): every lane gets all four full gate sums
        acc0 = dpp_add<0xB1>(acc0); acc0 = dpp_add<0x4E>(acc0);
        acc1 = dpp_add<0xB1>(acc1); acc1 = dpp_add<0x4E>(acc1);
        acc2 = dpp_add<0xB1>(acc2); acc2 = dpp_add<0x4E>(acc2);
        acc3 = dpp_add<0xB1>(acc3); acc3 = dpp_add<0x4E>(acc3);

        // lane s activates gate s only (i,f,o: sigmoid; g: tanh = 2*sig(2x)-1)
        const float a  = (s & 1) ? ((s & 2) ? acc3 : acc1)
                                 : ((s & 2) ? acc2 : acc0);
        const float pre = is_g ? (a + a) : a;
        const float e   = __expf(-pre);
        const float v   = 1.0f / (1.0f + e);
        const float act = is_g ? (v + v - 1.0f) : v;

        // redistribute the four activations within the quad (DPP broadcasts)
        const float ig = dpp_mov<0x00>(act);
        const float fg = dpp_mov<0x55>(act);
        const float gg = dpp_mov<0xAA>(act);
        const float og = dpp_mov<0xFF>(act);

        c = fmaf(fg, c, ig * gg);
        const float e2 = __expf(-2.0f * c);
        const float th = 2.0f / (1.0f + e2) - 1.0f;
        const float h  = og * th;

        if (active && s == 0)
            h_buf[(t + 1) & 1][j] = (_Float16)h;
        __syncthreads();
    }

    // head: lin = W1 @ h + b1 (64), out = W2 @ lin + b2 (scalar)
    if (tid < 64) {
        const float* r = W1 + tid * HID;
        float a = 0.0f;
        for (int k = 0; k < HID; ++k)
            a = fmaf(r[k], (float)h_buf[0][k], a);   // T even -> final h in buf 0
        red_lds[tid] = a + b1[tid];
    }
    __syncthreads();
    if (tid == 0) {
        float a = b2[0];
        for (int k = 0; k < 64; ++k)
            a = fmaf(W2[k], red_lds[k], a);
        out[0] = a;
    }
}

extern "C" void kernel_launch(void* const* d_in, const int* in_sizes, int n_in,
                              void* d_out, int out_size, void* d_ws, size_t ws_size,
                              hipStream_t stream) {
    lstm_caviar_kernel<<<1, NTH, 0, stream>>>(
        (const float*)d_in[0],  // input_seq
        (const float*)d_in[1],  // W_ih
        (const float*)d_in[2],  // W_hh
        (const float*)d_in[3],  // b_ih
        (const float*)d_in[4],  // b_hh
        (const float*)d_in[5],  // W1
        (const float*)d_in[6],  // b1
        (const float*)d_in[7],  // W2
        (const float*)d_in[8],  // b2
        (float*)d_out);
}